// Round 1
// baseline (314.450 us; speedup 1.0000x reference)
//
#include <hip/hip_runtime.h>
#include <hip/hip_bf16.h>
#include <math.h>
#include <stdint.h>

#define N_NODES 40000
#define N_EDGES 640000
#define F_IN    512
#define F_OUT   32
#define HEADS   8
#define C_OUT   (HEADS * F_OUT)   // 256
#define NEG_SLOPE 0.2f
#define EPS_F   1e-16f

typedef __attribute__((ext_vector_type(8)))  short  short8;
typedef __attribute__((ext_vector_type(4)))  short  short4v;
typedef __attribute__((ext_vector_type(16))) float  float16v;

// truncating fp32 -> (hi,lo) bf16 split: hi+lo represents f to ~2^-17 rel
__device__ __forceinline__ void splitT(float f, unsigned short& hi, unsigned short& lo) {
    unsigned u = __float_as_uint(f);
    hi = (unsigned short)(u >> 16);
    float r = f - __uint_as_float(u & 0xFFFF0000u);
    lo = (unsigned short)(__float_as_uint(r) >> 16);
}

__device__ __forceinline__ unsigned short f2bf(float f) {
    unsigned u = __float_as_uint(f);
    return (unsigned short)((u + 0x7FFF + ((u >> 16) & 1)) >> 16);
}

// ---------------------------------------------------------------------------
// K0: fused pack_W + count_edges (independent work, one launch).
// Blocks [0,512): pack W into per-lane B-fragment layout for
// mfma_f32_32x32x16_bf16.
// Bp[strip(2)][wc(2)][ktg(32)][ni(2)][lane(64)][j(8)], value =
//   B[k = ktg*16 + (lane>>5)*8 + j][col = strip*128 + wc*64 + ni*32 + (lane&31)]
// where B[k][col] = W[col>>5][k][col&31].
// Blocks [512, 512+2500): per-dst in-degree counts.
// ---------------------------------------------------------------------------
__global__ __launch_bounds__(256) void pack_and_count(const float* __restrict__ W,
                                                      unsigned short* __restrict__ Bp,
                                                      const int* __restrict__ dst,
                                                      int* __restrict__ count) {
    if (blockIdx.x < 512) {
        int tid = blockIdx.x * 256 + threadIdx.x;   // 131072 total
        int j    = tid & 7;
        int L    = (tid >> 3) & 63;
        int ni   = (tid >> 9) & 1;
        int ktg  = (tid >> 10) & 31;
        int wc   = (tid >> 15) & 1;
        int strip= tid >> 16;
        int k    = ktg * 16 + (L >> 5) * 8 + j;
        int col  = strip * 128 + wc * 64 + ni * 32 + (L & 31);
        int hh = col >> 5, f = col & 31;
        Bp[tid] = f2bf(W[hh * (F_IN * F_OUT) + k * F_OUT + f]);
    } else {
        int e = (blockIdx.x - 512) * 256 + threadIdx.x;
        atomicAdd(&count[dst[e]], 1);
    }
}

// ---------------------------------------------------------------------------
// K1: MFMA projection GEMM, 32x32x16 bf16, 2-term split ((x_hi+x_lo)*B_hi).
// Block: 4 waves (2x2), tile 128 rows x 128 cols; grid (313, 2). BK=64.
// A staged in LDS (stride 66 shorts = 33 banks -> conflict-free frag reads);
// B fragments loaded register-direct from L2-resident packed buffer.
// Epilogue: h16 stores + fused fp32-exact attention scores.
// ---------------------------------------------------------------------------
#define AS 66   // k-stride in shorts: 64 + 2 pad (33 banks, odd -> bijection)

__global__ __launch_bounds__(256, 3) void gemm_mfma(const float* __restrict__ x,
                                                    const unsigned short* __restrict__ Bp,
                                                    const float* __restrict__ a_src,
                                                    const float* __restrict__ a_dst,
                                                    unsigned short* __restrict__ h16,
                                                    float* __restrict__ s_src,
                                                    float* __restrict__ s_dst) {
    __shared__ unsigned short As_hi[128 * AS];
    __shared__ unsigned short As_lo[128 * AS];

    const int t = threadIdx.x;
    const int wave = t >> 6, L = t & 63;
    const int wr = wave & 1, wc = wave >> 1;
    const int r31 = L & 31, half = L >> 5;
    const int strip = blockIdx.y;
    const int n0 = blockIdx.x * 128;

    float16v acc[2][2];
#pragma unroll
    for (int i = 0; i < 2; ++i)
#pragma unroll
        for (int j = 0; j < 2; ++j)
#pragma unroll
            for (int r = 0; r < 16; ++r) acc[i][j][r] = 0.f;

    const int kcol = (t & 15) * 4;
    const int rbase = t >> 4;

    for (int st = 0; st < 8; ++st) {
        const int kb = st * 64;
        __syncthreads();
        // ---- stage A: 128 rows x 64 k fp32 -> bf16 hi/lo in LDS ----
#pragma unroll
        for (int it = 0; it < 8; ++it) {
            int r = rbase + it * 16;
            int rg = n0 + r; rg = rg < N_NODES ? rg : N_NODES - 1;
            float4 v = *(const float4*)&x[(size_t)rg * F_IN + kb + kcol];
            unsigned short h0, h1, h2, h3, l0, l1, l2, l3;
            splitT(v.x, h0, l0); splitT(v.y, h1, l1);
            splitT(v.z, h2, l2); splitT(v.w, h3, l3);
            int off = r * AS + kcol;
            *(short4v*)&As_hi[off] = (short4v){(short)h0, (short)h1, (short)h2, (short)h3};
            *(short4v*)&As_lo[off] = (short4v){(short)l0, (short)l1, (short)l2, (short)l3};
        }
        __syncthreads();

        // ---- B fragments: register-direct, 8 coalesced dwordx4 per wave ----
        short8 breg[4][2];
#pragma unroll
        for (int kt = 0; kt < 4; ++kt)
#pragma unroll
            for (int ni = 0; ni < 2; ++ni) {
                size_t idx = ((((size_t)(strip * 2 + wc) * 32 + (st * 4 + kt)) * 2 + ni) * 64 + L) * 8;
                breg[kt][ni] = *(const short8*)&Bp[idx];
            }

        // ---- MFMA: 4 k-steps of 16, 2 mi x 2 ni x 2 terms ----
#pragma unroll
        for (int kt = 0; kt < 4; ++kt) {
            short8 ah[2], al[2];
#pragma unroll
            for (int mi = 0; mi < 2; ++mi) {
                int off = (wr * 64 + mi * 32 + r31) * AS + kt * 16 + half * 8;
                ah[mi] = *(const short8*)&As_hi[off];
                al[mi] = *(const short8*)&As_lo[off];
            }
#pragma unroll
            for (int mi = 0; mi < 2; ++mi)
#pragma unroll
                for (int ni = 0; ni < 2; ++ni) {
                    acc[mi][ni] = __builtin_amdgcn_mfma_f32_32x32x16_bf16(ah[mi], breg[kt][ni], acc[mi][ni], 0, 0, 0);
                    acc[mi][ni] = __builtin_amdgcn_mfma_f32_32x32x16_bf16(al[mi], breg[kt][ni], acc[mi][ni], 0, 0, 0);
                }
        }
    }

    // ---- epilogue 1: h16 stores ----
    // C/D layout (32x32): col = lane&31, row = (reg&3) + 8*(reg>>2) + 4*half
#pragma unroll
    for (int mi = 0; mi < 2; ++mi)
#pragma unroll
        for (int ni = 0; ni < 2; ++ni) {
            int colb = strip * 128 + wc * 64 + ni * 32 + r31;
#pragma unroll
            for (int r = 0; r < 16; ++r) {
                int row = n0 + wr * 64 + mi * 32 + (r & 3) + 8 * (r >> 2) + 4 * half;
                if (row < N_NODES)
                    h16[(size_t)row * C_OUT + colb] = f2bf(acc[mi][ni][r]);
            }
        }

    // ---- epilogue 2: fused attention scores (fp32-exact) ----
    // ni-frag covers exactly one head: hh = strip*4 + wc*2 + ni
#pragma unroll
    for (int ni = 0; ni < 2; ++ni) {
        int hh = strip * 4 + wc * 2 + ni;
        float af = a_src[hh * 32 + r31];
        float df = a_dst[hh * 32 + r31];
#pragma unroll
        for (int mi = 0; mi < 2; ++mi)
#pragma unroll
            for (int r = 0; r < 16; ++r) {
                float v = acc[mi][ni][r];
                float vs = v * af;
                float vd = v * df;
#pragma unroll
                for (int m = 1; m < 32; m <<= 1) {
                    vs += __shfl_xor(vs, m, 64);
                    vd += __shfl_xor(vd, m, 64);
                }
                if (r31 == 0) {
                    int row = n0 + wr * 64 + mi * 32 + (r & 3) + 8 * (r >> 2) + 4 * half;
                    if (row < N_NODES) {
                        s_src[row * 8 + hh] = vs;
                        s_dst[row * 8 + hh] = vd;
                    }
                }
            }
    }
}

// ---------------------------------------------------------------------------
// K4a: 40-block local exclusive scan (1000/block) + per-block totals
// ---------------------------------------------------------------------------
__global__ __launch_bounds__(1024) void scan_local(const int* __restrict__ count,
                                                   int* __restrict__ row_excl,
                                                   int* __restrict__ cursor,
                                                   int* __restrict__ btot) {
    __shared__ int woff[16];
    __shared__ int tot_s;
    const int b = blockIdx.x, t = threadIdx.x;
    const int lane = t & 63, wid = t >> 6;
    const int i = b * 1000 + t;
    int v = (t < 1000) ? count[i] : 0;
    int inc = v;
#pragma unroll
    for (int d = 1; d < 64; d <<= 1) {
        int u = __shfl_up(inc, d, 64);
        if (lane >= d) inc += u;
    }
    if (lane == 63) woff[wid] = inc;
    __syncthreads();
    if (t < 16) {
        int s = woff[t];
        int sc = s;
#pragma unroll
        for (int d = 1; d < 16; d <<= 1) {
            int u = __shfl_up(sc, d, 64);
            if (t >= d) sc += u;
        }
        woff[t] = sc - s;
        if (t == 15) tot_s = sc;
    }
    __syncthreads();
    int excl = woff[wid] + inc - v;
    if (t < 1000) { row_excl[i] = excl; cursor[i] = excl; }
    if (t == 0) btot[b] = tot_s;
}

// K4b: exclusive scan of the 40 block totals -> boff
__global__ __launch_bounds__(64) void scan_tots(const int* __restrict__ btot,
                                                int* __restrict__ boff) {
    const int t = threadIdx.x;
    int v = (t < 40) ? btot[t] : 0;
    int inc = v;
#pragma unroll
    for (int d = 1; d < 64; d <<= 1) {
        int u = __shfl_up(inc, d, 64);
        if (t >= d) inc += u;
    }
    if (t < 40) boff[t] = inc - v;
}

// ---------------------------------------------------------------------------
// K5: slim scatter — only the dst-sorted src ids (4 B/edge).
// ---------------------------------------------------------------------------
__global__ __launch_bounds__(256) void scatter_edges(const int* __restrict__ src,
                                                     const int* __restrict__ dst,
                                                     int* __restrict__ cursor,
                                                     const int* __restrict__ boff,
                                                     int* __restrict__ src_sorted) {
    int e = blockIdx.x * 256 + threadIdx.x;
    int s = src[e], d = dst[e];
    int pos = atomicAdd(&cursor[d], 1) + boff[d / 1000];
    src_sorted[pos] = s;
}

// ---------------------------------------------------------------------------
// K6: aggregation. One WAVE per node; lane owns 4 channels; 8-edge batches
// for deeper MLP (8 independent h16 rows = 4 KB in flight per wave).
// w = exp(leaky(s_src[s]+s_dst[n])) recomputed inline (fp32 exact).
// rem is wave-uniform -> no divergence; inactive slots read node 0 (L1 hit)
// with w=0.
// ---------------------------------------------------------------------------
__global__ __launch_bounds__(256) void aggregate(const int* __restrict__ src_sorted,
                                                 const unsigned short* __restrict__ h16,
                                                 const float* __restrict__ s_src,
                                                 const float* __restrict__ s_dst,
                                                 const int* __restrict__ row_excl,
                                                 const int* __restrict__ boff,
                                                 const int* __restrict__ count,
                                                 const float* __restrict__ bias,
                                                 float* __restrict__ out) {
    const int t = threadIdx.x;
    const int wave = t >> 6, lane = t & 63;
    const int n = blockIdx.x * 4 + wave;
    const int ch0 = lane * 4;
    const int hh = lane >> 3;
    const int start = row_excl[n] + boff[n / 1000];
    const int cnt = count[n];
    const float sd = s_dst[n * 8 + hh];

    float a0 = 0.f, a1 = 0.f, a2 = 0.f, a3 = 0.f, den = 0.f;

    auto bf2f = [](short v) { return __uint_as_float(((unsigned)(unsigned short)v) << 16); };

    for (int base = 0; base < cnt; base += 8) {
        int rem = cnt - base;
        int idx = start + base;
        int s[8];
#pragma unroll
        for (int u = 0; u < 8; ++u)
            s[u] = (u < rem) ? src_sorted[idx + u] : 0;

        float w[8];
#pragma unroll
        for (int u = 0; u < 8; ++u) {
            float e = s_src[s[u] * 8 + hh] + sd;
            e = e >= 0.f ? e : NEG_SLOPE * e;
            w[u] = (u < rem) ? __expf(e) : 0.f;
        }

        short4v v[8];
#pragma unroll
        for (int u = 0; u < 8; ++u)
            v[u] = *(const short4v*)&h16[(size_t)s[u] * C_OUT + ch0];

#pragma unroll
        for (int u = 0; u < 8; ++u) {
            a0 += w[u] * bf2f(v[u][0]);
            a1 += w[u] * bf2f(v[u][1]);
            a2 += w[u] * bf2f(v[u][2]);
            a3 += w[u] * bf2f(v[u][3]);
            den += w[u];
        }
    }

    float inv = 1.0f / (den + EPS_F);
    float4 b4 = *(const float4*)&bias[ch0];
    float4 o;
    o.x = a0 * inv + b4.x;
    o.y = a1 * inv + b4.y;
    o.z = a2 * inv + b4.z;
    o.w = a3 * inv + b4.w;
    *(float4*)&out[(size_t)n * C_OUT + ch0] = o;
}

// ---------------------------------------------------------------------------
extern "C" void kernel_launch(void* const* d_in, const int* in_sizes, int n_in,
                              void* d_out, int out_size, void* d_ws, size_t ws_size,
                              hipStream_t stream) {
    const float* x     = (const float*)d_in[0];
    const int*   eidx  = (const int*)d_in[1];
    const float* W     = (const float*)d_in[2];
    const float* a_src = (const float*)d_in[3];
    const float* a_dst = (const float*)d_in[4];
    const float* bias  = (const float*)d_in[5];
    float* out = (float*)d_out;

    const int* src = eidx;
    const int* dst = eidx + N_EDGES;

    char* p = (char*)d_ws;
    auto carve = [&](size_t bytes) {
        char* r = p;
        p += (bytes + 255) & ~(size_t)255;
        return r;
    };
    unsigned short* h16 = (unsigned short*)carve((size_t)N_NODES * C_OUT * 2); // 20.48 MB
    float* s_src      = (float*)carve((size_t)N_NODES * HEADS * 4);
    float* s_dst      = (float*)carve((size_t)N_NODES * HEADS * 4);
    int*   src_sorted = (int*)carve((size_t)N_EDGES * 4);
    int*   count      = (int*)carve((size_t)N_NODES * 4);
    int*   row_excl   = (int*)carve((size_t)N_NODES * 4);
    int*   cursor     = (int*)carve((size_t)N_NODES * 4);
    int*   btot       = (int*)carve(64 * 4);
    int*   boff       = (int*)carve(64 * 4);
    unsigned short* Bp = (unsigned short*)carve((size_t)131072 * 2);           // 256 KB

    hipMemsetAsync(count, 0, (size_t)N_NODES * 4, stream);

    pack_and_count<<<512 + N_EDGES / 256, 256, 0, stream>>>(W, Bp, dst, count);
    dim3 ggrid(313, 2);
    gemm_mfma<<<ggrid, 256, 0, stream>>>(x, Bp, a_src, a_dst, h16, s_src, s_dst);
    scan_local<<<40, 1024, 0, stream>>>(count, row_excl, cursor, btot);
    scan_tots<<<1, 64, 0, stream>>>(btot, boff);
    scatter_edges<<<N_EDGES / 256, 256, 0, stream>>>(src, dst, cursor, boff, src_sorted);
    aggregate<<<N_NODES / 4, 256, 0, stream>>>(src_sorted, h16, s_src, s_dst,
                                               row_excl, boff, count, bias, out);
}

// Round 2
// 306.510 us; speedup vs baseline: 1.0259x; 1.0259x over previous
//
#include <hip/hip_runtime.h>
#include <hip/hip_bf16.h>
#include <math.h>
#include <stdint.h>

#define N_NODES 40000
#define N_EDGES 640000
#define F_IN    512
#define F_OUT   32
#define HEADS   8
#define C_OUT   (HEADS * F_OUT)   // 256
#define NEG_SLOPE 0.2f
#define EPS_F   1e-16f

typedef __attribute__((ext_vector_type(8)))  short  short8;
typedef __attribute__((ext_vector_type(4)))  short  short4v;
typedef __attribute__((ext_vector_type(16))) float  float16v;

// truncating fp32 -> (hi,lo) bf16 split: hi+lo represents f to ~2^-17 rel
__device__ __forceinline__ void splitT(float f, unsigned short& hi, unsigned short& lo) {
    unsigned u = __float_as_uint(f);
    hi = (unsigned short)(u >> 16);
    float r = f - __uint_as_float(u & 0xFFFF0000u);
    lo = (unsigned short)(__float_as_uint(r) >> 16);
}

__device__ __forceinline__ unsigned short f2bf(float f) {
    unsigned u = __float_as_uint(f);
    return (unsigned short)((u + 0x7FFF + ((u >> 16) & 1)) >> 16);
}

// ---------------------------------------------------------------------------
// K0: fused pack_W + count_edges (independent work, one launch).
// Blocks [0,512): pack W into per-lane B-fragment layout for
// mfma_f32_32x32x16_bf16.
// Bp[wc(4)][ktg(32)][ni(2)][lane(64)][j(8)], value =
//   B[k = ktg*16 + (lane>>5)*8 + j][col = wc*64 + ni*32 + (lane&31)]
// where B[k][col] = W[col>>5][k][col&31].
// Blocks [512, 512+2500): per-dst in-degree counts.
// ---------------------------------------------------------------------------
__global__ __launch_bounds__(256) void pack_and_count(const float* __restrict__ W,
                                                      unsigned short* __restrict__ Bp,
                                                      const int* __restrict__ dst,
                                                      int* __restrict__ count) {
    if (blockIdx.x < 512) {
        int tid = blockIdx.x * 256 + threadIdx.x;   // 131072 total
        int j    = tid & 7;
        int L    = (tid >> 3) & 63;
        int ni   = (tid >> 9) & 1;
        int ktg  = (tid >> 10) & 31;
        int wc   = tid >> 15;                        // 0..3
        int k    = ktg * 16 + (L >> 5) * 8 + j;
        int col  = wc * 64 + ni * 32 + (L & 31);
        int hh = col >> 5, f = col & 31;
        Bp[tid] = f2bf(W[hh * (F_IN * F_OUT) + k * F_OUT + f]);
    } else {
        int e = (blockIdx.x - 512) * 256 + threadIdx.x;
        atomicAdd(&count[dst[e]], 1);
    }
}

// ---------------------------------------------------------------------------
// K1: MFMA projection GEMM, 32x32x16 bf16, 2-term split ((x_hi+x_lo)*B_hi).
// Single pass over all 256 output cols: block = 512 threads (8 waves, 2x4),
// tile 64 rows x 256 cols; grid 625 (exact: 625*64 = 40000 -> no guards).
// Register double-buffered staging: next K-tile's global loads issue at the
// top of the iteration (before the LDS write of the current tile), so HBM
// latency hides under write + barrier + B-frags + MFMA.
// A staged in LDS (stride 66 shorts = 33 banks -> conflict-free frag reads);
// B fragments register-direct from the L2-resident packed buffer.
// Epilogue: h16 stores + fused fp32-exact attention scores.
// ---------------------------------------------------------------------------
#define AS 66   // k-stride in shorts: 64 + 2 pad (33 banks, odd -> bijection)

__global__ __launch_bounds__(512, 4) void gemm_mfma(const float* __restrict__ x,
                                                    const unsigned short* __restrict__ Bp,
                                                    const float* __restrict__ a_src,
                                                    const float* __restrict__ a_dst,
                                                    unsigned short* __restrict__ h16,
                                                    float* __restrict__ s_src,
                                                    float* __restrict__ s_dst) {
    __shared__ unsigned short As_hi[64 * AS];
    __shared__ unsigned short As_lo[64 * AS];

    const int t = threadIdx.x;
    const int wave = t >> 6, L = t & 63;
    const int wr = wave & 1, wc = wave >> 1;      // wr in 0..1, wc in 0..3
    const int r31 = L & 31, half = L >> 5;
    const int n0 = blockIdx.x * 64;

    float16v acc[2];
#pragma unroll
    for (int ni = 0; ni < 2; ++ni)
#pragma unroll
        for (int r = 0; r < 16; ++r) acc[ni][r] = 0.f;

    const int kcol = (t & 15) * 4;   // k offset within 64-wide K-tile
    const int rbase = t >> 4;        // 0..31, rows rbase and rbase+32

    // ping-pong staging registers (static indices after full unroll)
    float4 stg[2][2];
#pragma unroll
    for (int it = 0; it < 2; ++it)
        stg[0][it] = *(const float4*)&x[(size_t)(n0 + rbase + it * 32) * F_IN + kcol];

#pragma unroll
    for (int st = 0; st < 8; ++st) {
        const int cur = st & 1, nxt = cur ^ 1;
        __syncthreads();   // previous iteration's frag reads done

        // ---- issue next K-tile's loads early (overlap with everything below)
        if (st < 7) {
            const int kb2 = (st + 1) * 64;
#pragma unroll
            for (int it = 0; it < 2; ++it)
                stg[nxt][it] = *(const float4*)&x[(size_t)(n0 + rbase + it * 32) * F_IN + kb2 + kcol];
        }

        // ---- write current tile: fp32 -> bf16 hi/lo into LDS ----
#pragma unroll
        for (int it = 0; it < 2; ++it) {
            float4 v = stg[cur][it];
            unsigned short h0, h1, h2, h3, l0, l1, l2, l3;
            splitT(v.x, h0, l0); splitT(v.y, h1, l1);
            splitT(v.z, h2, l2); splitT(v.w, h3, l3);
            int off = (rbase + it * 32) * AS + kcol;
            *(short4v*)&As_hi[off] = (short4v){(short)h0, (short)h1, (short)h2, (short)h3};
            *(short4v*)&As_lo[off] = (short4v){(short)l0, (short)l1, (short)l2, (short)l3};
        }
        __syncthreads();

        // ---- B fragments: register-direct, coalesced dwordx4 from L2 ----
        short8 breg[4][2];
#pragma unroll
        for (int kt = 0; kt < 4; ++kt)
#pragma unroll
            for (int ni = 0; ni < 2; ++ni) {
                size_t idx = ((((size_t)wc * 32 + (st * 4 + kt)) * 2 + ni) * 64 + L) * 8;
                breg[kt][ni] = *(const short8*)&Bp[idx];
            }

        // ---- MFMA: 4 k-steps of 16, 2 ni x 2 terms ----
#pragma unroll
        for (int kt = 0; kt < 4; ++kt) {
            int off = (wr * 32 + r31) * AS + kt * 16 + half * 8;
            short8 ah = *(const short8*)&As_hi[off];
            short8 al = *(const short8*)&As_lo[off];
#pragma unroll
            for (int ni = 0; ni < 2; ++ni) {
                acc[ni] = __builtin_amdgcn_mfma_f32_32x32x16_bf16(ah, breg[kt][ni], acc[ni], 0, 0, 0);
                acc[ni] = __builtin_amdgcn_mfma_f32_32x32x16_bf16(al, breg[kt][ni], acc[ni], 0, 0, 0);
            }
        }
    }

    // ---- epilogue 1: h16 stores ----
    // C/D layout (32x32): col = lane&31, row = (reg&3) + 8*(reg>>2) + 4*half
#pragma unroll
    for (int ni = 0; ni < 2; ++ni) {
        int colb = wc * 64 + ni * 32 + r31;
#pragma unroll
        for (int r = 0; r < 16; ++r) {
            int row = n0 + wr * 32 + (r & 3) + 8 * (r >> 2) + 4 * half;
            h16[(size_t)row * C_OUT + colb] = f2bf(acc[ni][r]);
        }
    }

    // ---- epilogue 2: fused attention scores (fp32-exact) ----
    // ni-frag covers exactly one head: hh = wc*2 + ni
#pragma unroll
    for (int ni = 0; ni < 2; ++ni) {
        int hh = wc * 2 + ni;
        float af = a_src[hh * 32 + r31];
        float df = a_dst[hh * 32 + r31];
#pragma unroll
        for (int r = 0; r < 16; ++r) {
            float v = acc[ni][r];
            float vs = v * af;
            float vd = v * df;
#pragma unroll
            for (int m = 1; m < 32; m <<= 1) {
                vs += __shfl_xor(vs, m, 64);
                vd += __shfl_xor(vd, m, 64);
            }
            if (r31 == 0) {
                int row = n0 + wr * 32 + (r & 3) + 8 * (r >> 2) + 4 * half;
                s_src[row * 8 + hh] = vs;
                s_dst[row * 8 + hh] = vd;
            }
        }
    }
}

// ---------------------------------------------------------------------------
// K4a: 40-block local exclusive scan (1000/block) + per-block totals
// ---------------------------------------------------------------------------
__global__ __launch_bounds__(1024) void scan_local(const int* __restrict__ count,
                                                   int* __restrict__ row_excl,
                                                   int* __restrict__ cursor,
                                                   int* __restrict__ btot) {
    __shared__ int woff[16];
    __shared__ int tot_s;
    const int b = blockIdx.x, t = threadIdx.x;
    const int lane = t & 63, wid = t >> 6;
    const int i = b * 1000 + t;
    int v = (t < 1000) ? count[i] : 0;
    int inc = v;
#pragma unroll
    for (int d = 1; d < 64; d <<= 1) {
        int u = __shfl_up(inc, d, 64);
        if (lane >= d) inc += u;
    }
    if (lane == 63) woff[wid] = inc;
    __syncthreads();
    if (t < 16) {
        int s = woff[t];
        int sc = s;
#pragma unroll
        for (int d = 1; d < 16; d <<= 1) {
            int u = __shfl_up(sc, d, 64);
            if (t >= d) sc += u;
        }
        woff[t] = sc - s;
        if (t == 15) tot_s = sc;
    }
    __syncthreads();
    int excl = woff[wid] + inc - v;
    if (t < 1000) { row_excl[i] = excl; cursor[i] = excl; }
    if (t == 0) btot[b] = tot_s;
}

// K4b: exclusive scan of the 40 block totals -> boff
__global__ __launch_bounds__(64) void scan_tots(const int* __restrict__ btot,
                                                int* __restrict__ boff) {
    const int t = threadIdx.x;
    int v = (t < 40) ? btot[t] : 0;
    int inc = v;
#pragma unroll
    for (int d = 1; d < 64; d <<= 1) {
        int u = __shfl_up(inc, d, 64);
        if (t >= d) inc += u;
    }
    if (t < 40) boff[t] = inc - v;
}

// ---------------------------------------------------------------------------
// K5: slim scatter — only the dst-sorted src ids (4 B/edge).
// ---------------------------------------------------------------------------
__global__ __launch_bounds__(256) void scatter_edges(const int* __restrict__ src,
                                                     const int* __restrict__ dst,
                                                     int* __restrict__ cursor,
                                                     const int* __restrict__ boff,
                                                     int* __restrict__ src_sorted) {
    int e = blockIdx.x * 256 + threadIdx.x;
    int s = src[e], d = dst[e];
    int pos = atomicAdd(&cursor[d], 1) + boff[d / 1000];
    src_sorted[pos] = s;
}

// ---------------------------------------------------------------------------
// K6: aggregation. One WAVE per node; lane owns 4 channels; 8-edge batches
// for deeper MLP (8 independent h16 rows = 4 KB in flight per wave).
// w = exp(leaky(s_src[s]+s_dst[n])) recomputed inline (fp32 exact).
// rem is wave-uniform -> no divergence; inactive slots read node 0 (L1 hit)
// with w=0.
// ---------------------------------------------------------------------------
__global__ __launch_bounds__(256) void aggregate(const int* __restrict__ src_sorted,
                                                 const unsigned short* __restrict__ h16,
                                                 const float* __restrict__ s_src,
                                                 const float* __restrict__ s_dst,
                                                 const int* __restrict__ row_excl,
                                                 const int* __restrict__ boff,
                                                 const int* __restrict__ count,
                                                 const float* __restrict__ bias,
                                                 float* __restrict__ out) {
    const int t = threadIdx.x;
    const int wave = t >> 6, lane = t & 63;
    const int n = blockIdx.x * 4 + wave;
    const int ch0 = lane * 4;
    const int hh = lane >> 3;
    const int start = row_excl[n] + boff[n / 1000];
    const int cnt = count[n];
    const float sd = s_dst[n * 8 + hh];

    float a0 = 0.f, a1 = 0.f, a2 = 0.f, a3 = 0.f, den = 0.f;

    auto bf2f = [](short v) { return __uint_as_float(((unsigned)(unsigned short)v) << 16); };

    for (int base = 0; base < cnt; base += 8) {
        int rem = cnt - base;
        int idx = start + base;
        int s[8];
#pragma unroll
        for (int u = 0; u < 8; ++u)
            s[u] = (u < rem) ? src_sorted[idx + u] : 0;

        float w[8];
#pragma unroll
        for (int u = 0; u < 8; ++u) {
            float e = s_src[s[u] * 8 + hh] + sd;
            e = e >= 0.f ? e : NEG_SLOPE * e;
            w[u] = (u < rem) ? __expf(e) : 0.f;
        }

        short4v v[8];
#pragma unroll
        for (int u = 0; u < 8; ++u)
            v[u] = *(const short4v*)&h16[(size_t)s[u] * C_OUT + ch0];

#pragma unroll
        for (int u = 0; u < 8; ++u) {
            a0 += w[u] * bf2f(v[u][0]);
            a1 += w[u] * bf2f(v[u][1]);
            a2 += w[u] * bf2f(v[u][2]);
            a3 += w[u] * bf2f(v[u][3]);
            den += w[u];
        }
    }

    float inv = 1.0f / (den + EPS_F);
    float4 b4 = *(const float4*)&bias[ch0];
    float4 o;
    o.x = a0 * inv + b4.x;
    o.y = a1 * inv + b4.y;
    o.z = a2 * inv + b4.z;
    o.w = a3 * inv + b4.w;
    *(float4*)&out[(size_t)n * C_OUT + ch0] = o;
}

// ---------------------------------------------------------------------------
extern "C" void kernel_launch(void* const* d_in, const int* in_sizes, int n_in,
                              void* d_out, int out_size, void* d_ws, size_t ws_size,
                              hipStream_t stream) {
    const float* x     = (const float*)d_in[0];
    const int*   eidx  = (const int*)d_in[1];
    const float* W     = (const float*)d_in[2];
    const float* a_src = (const float*)d_in[3];
    const float* a_dst = (const float*)d_in[4];
    const float* bias  = (const float*)d_in[5];
    float* out = (float*)d_out;

    const int* src = eidx;
    const int* dst = eidx + N_EDGES;

    char* p = (char*)d_ws;
    auto carve = [&](size_t bytes) {
        char* r = p;
        p += (bytes + 255) & ~(size_t)255;
        return r;
    };
    unsigned short* h16 = (unsigned short*)carve((size_t)N_NODES * C_OUT * 2); // 20.48 MB
    float* s_src      = (float*)carve((size_t)N_NODES * HEADS * 4);
    float* s_dst      = (float*)carve((size_t)N_NODES * HEADS * 4);
    int*   src_sorted = (int*)carve((size_t)N_EDGES * 4);
    int*   count      = (int*)carve((size_t)N_NODES * 4);
    int*   row_excl   = (int*)carve((size_t)N_NODES * 4);
    int*   cursor     = (int*)carve((size_t)N_NODES * 4);
    int*   btot       = (int*)carve(64 * 4);
    int*   boff       = (int*)carve(64 * 4);
    unsigned short* Bp = (unsigned short*)carve((size_t)131072 * 2);           // 256 KB

    hipMemsetAsync(count, 0, (size_t)N_NODES * 4, stream);

    pack_and_count<<<512 + N_EDGES / 256, 256, 0, stream>>>(W, Bp, dst, count);
    gemm_mfma<<<625, 512, 0, stream>>>(x, Bp, a_src, a_dst, h16, s_src, s_dst);
    scan_local<<<40, 1024, 0, stream>>>(count, row_excl, cursor, btot);
    scan_tots<<<1, 64, 0, stream>>>(btot, boff);
    scatter_edges<<<N_EDGES / 256, 256, 0, stream>>>(src, dst, cursor, boff, src_sorted);
    aggregate<<<N_NODES / 4, 256, 0, stream>>>(src_sorted, h16, s_src, s_dst,
                                               row_excl, boff, count, bias, out);
}

// Round 3
// 300.291 us; speedup vs baseline: 1.0472x; 1.0207x over previous
//
#include <hip/hip_runtime.h>
#include <hip/hip_bf16.h>
#include <math.h>
#include <stdint.h>

#define N_NODES 40000
#define N_EDGES 640000
#define F_IN    512
#define F_OUT   32
#define HEADS   8
#define C_OUT   (HEADS * F_OUT)   // 256
#define NEG_SLOPE 0.2f
#define EPS_F   1e-16f

typedef __attribute__((ext_vector_type(8)))  short  short8;
typedef __attribute__((ext_vector_type(4)))  short  short4v;
typedef __attribute__((ext_vector_type(16))) float  float16v;

// truncating fp32 -> (hi,lo) bf16 split: hi+lo represents f to ~2^-17 rel
__device__ __forceinline__ void splitT(float f, unsigned short& hi, unsigned short& lo) {
    unsigned u = __float_as_uint(f);
    hi = (unsigned short)(u >> 16);
    float r = f - __uint_as_float(u & 0xFFFF0000u);
    lo = (unsigned short)(__float_as_uint(r) >> 16);
}

__device__ __forceinline__ unsigned short f2bf(float f) {
    unsigned u = __float_as_uint(f);
    return (unsigned short)((u + 0x7FFF + ((u >> 16) & 1)) >> 16);
}

// ---------------------------------------------------------------------------
// K0: fused pack_W + count_edges (independent work, one launch).
// Blocks [0,512): pack W into per-lane B-fragment layout for
// mfma_f32_32x32x16_bf16.
// Bp[wc(4)][ktg(32)][ni(2)][lane(64)][j(8)], value =
//   B[k = ktg*16 + (lane>>5)*8 + j][col = wc*64 + ni*32 + (lane&31)]
// where B[k][col] = W[col>>5][k][col&31].
// Blocks [512, 512+2500): per-dst in-degree counts.
// ---------------------------------------------------------------------------
__global__ __launch_bounds__(256) void pack_and_count(const float* __restrict__ W,
                                                      unsigned short* __restrict__ Bp,
                                                      const int* __restrict__ dst,
                                                      int* __restrict__ count) {
    if (blockIdx.x < 512) {
        int tid = blockIdx.x * 256 + threadIdx.x;   // 131072 total
        int j    = tid & 7;
        int L    = (tid >> 3) & 63;
        int ni   = (tid >> 9) & 1;
        int ktg  = (tid >> 10) & 31;
        int wc   = tid >> 15;                        // 0..3
        int k    = ktg * 16 + (L >> 5) * 8 + j;
        int col  = wc * 64 + ni * 32 + (L & 31);
        int hh = col >> 5, f = col & 31;
        Bp[tid] = f2bf(W[hh * (F_IN * F_OUT) + k * F_OUT + f]);
    } else {
        int e = (blockIdx.x - 512) * 256 + threadIdx.x;
        atomicAdd(&count[dst[e]], 1);
    }
}

// ---------------------------------------------------------------------------
// K1: MFMA projection GEMM, 32x32x16 bf16, 2-term split ((x_hi+x_lo)*B_hi).
// Single pass over all 256 output cols: block = 512 threads (8 waves, 2x4),
// tile 64 rows x 256 cols; grid 625 (exact: 625*64 = 40000 -> no guards).
// Register double-buffered staging: next K-tile's global loads issue at the
// top of the iteration (before the LDS write of the current tile), so HBM
// latency hides under write + barrier + B-frags + MFMA.
// A staged in LDS (stride 66 shorts = 33 banks -> conflict-free frag reads);
// B fragments register-direct from the L2-resident packed buffer.
// Epilogue: h16 stores + fused fp32-exact attention scores.
// ---------------------------------------------------------------------------
#define AS 66   // k-stride in shorts: 64 + 2 pad (33 banks, odd -> bijection)

__global__ __launch_bounds__(512, 4) void gemm_mfma(const float* __restrict__ x,
                                                    const unsigned short* __restrict__ Bp,
                                                    const float* __restrict__ a_src,
                                                    const float* __restrict__ a_dst,
                                                    unsigned short* __restrict__ h16,
                                                    float* __restrict__ s_src,
                                                    float* __restrict__ s_dst) {
    __shared__ unsigned short As_hi[64 * AS];
    __shared__ unsigned short As_lo[64 * AS];

    const int t = threadIdx.x;
    const int wave = t >> 6, L = t & 63;
    const int wr = wave & 1, wc = wave >> 1;      // wr in 0..1, wc in 0..3
    const int r31 = L & 31, half = L >> 5;
    const int n0 = blockIdx.x * 64;

    float16v acc[2];
#pragma unroll
    for (int ni = 0; ni < 2; ++ni)
#pragma unroll
        for (int r = 0; r < 16; ++r) acc[ni][r] = 0.f;

    const int kcol = (t & 15) * 4;   // k offset within 64-wide K-tile
    const int rbase = t >> 4;        // 0..31, rows rbase and rbase+32

    // ping-pong staging registers (static indices after full unroll)
    float4 stg[2][2];
#pragma unroll
    for (int it = 0; it < 2; ++it)
        stg[0][it] = *(const float4*)&x[(size_t)(n0 + rbase + it * 32) * F_IN + kcol];

#pragma unroll
    for (int st = 0; st < 8; ++st) {
        const int cur = st & 1, nxt = cur ^ 1;
        __syncthreads();   // previous iteration's frag reads done

        // ---- issue next K-tile's loads early (overlap with everything below)
        if (st < 7) {
            const int kb2 = (st + 1) * 64;
#pragma unroll
            for (int it = 0; it < 2; ++it)
                stg[nxt][it] = *(const float4*)&x[(size_t)(n0 + rbase + it * 32) * F_IN + kb2 + kcol];
        }

        // ---- write current tile: fp32 -> bf16 hi/lo into LDS ----
#pragma unroll
        for (int it = 0; it < 2; ++it) {
            float4 v = stg[cur][it];
            unsigned short h0, h1, h2, h3, l0, l1, l2, l3;
            splitT(v.x, h0, l0); splitT(v.y, h1, l1);
            splitT(v.z, h2, l2); splitT(v.w, h3, l3);
            int off = (rbase + it * 32) * AS + kcol;
            *(short4v*)&As_hi[off] = (short4v){(short)h0, (short)h1, (short)h2, (short)h3};
            *(short4v*)&As_lo[off] = (short4v){(short)l0, (short)l1, (short)l2, (short)l3};
        }
        __syncthreads();

        // ---- B fragments: register-direct, coalesced dwordx4 from L2 ----
        short8 breg[4][2];
#pragma unroll
        for (int kt = 0; kt < 4; ++kt)
#pragma unroll
            for (int ni = 0; ni < 2; ++ni) {
                size_t idx = ((((size_t)wc * 32 + (st * 4 + kt)) * 2 + ni) * 64 + L) * 8;
                breg[kt][ni] = *(const short8*)&Bp[idx];
            }

        // ---- MFMA: 4 k-steps of 16, 2 ni x 2 terms ----
#pragma unroll
        for (int kt = 0; kt < 4; ++kt) {
            int off = (wr * 32 + r31) * AS + kt * 16 + half * 8;
            short8 ah = *(const short8*)&As_hi[off];
            short8 al = *(const short8*)&As_lo[off];
#pragma unroll
            for (int ni = 0; ni < 2; ++ni) {
                acc[ni] = __builtin_amdgcn_mfma_f32_32x32x16_bf16(ah, breg[kt][ni], acc[ni], 0, 0, 0);
                acc[ni] = __builtin_amdgcn_mfma_f32_32x32x16_bf16(al, breg[kt][ni], acc[ni], 0, 0, 0);
            }
        }
    }

    // ---- epilogue 1: h16 stores ----
    // C/D layout (32x32): col = lane&31, row = (reg&3) + 8*(reg>>2) + 4*half
#pragma unroll
    for (int ni = 0; ni < 2; ++ni) {
        int colb = wc * 64 + ni * 32 + r31;
#pragma unroll
        for (int r = 0; r < 16; ++r) {
            int row = n0 + wr * 32 + (r & 3) + 8 * (r >> 2) + 4 * half;
            h16[(size_t)row * C_OUT + colb] = f2bf(acc[ni][r]);
        }
    }

    // ---- epilogue 2: fused attention scores (fp32-exact) ----
    // ni-frag covers exactly one head: hh = wc*2 + ni
#pragma unroll
    for (int ni = 0; ni < 2; ++ni) {
        int hh = wc * 2 + ni;
        float af = a_src[hh * 32 + r31];
        float df = a_dst[hh * 32 + r31];
#pragma unroll
        for (int r = 0; r < 16; ++r) {
            float v = acc[ni][r];
            float vs = v * af;
            float vd = v * df;
#pragma unroll
            for (int m = 1; m < 32; m <<= 1) {
                vs += __shfl_xor(vs, m, 64);
                vd += __shfl_xor(vd, m, 64);
            }
            if (r31 == 0) {
                int row = n0 + wr * 32 + (r & 3) + 8 * (r >> 2) + 4 * half;
                s_src[row * 8 + hh] = vs;
                s_dst[row * 8 + hh] = vd;
            }
        }
    }
}

// ---------------------------------------------------------------------------
// K4a: 40-block local exclusive scan (1000/block) + per-block totals
// ---------------------------------------------------------------------------
__global__ __launch_bounds__(1024) void scan_local(const int* __restrict__ count,
                                                   int* __restrict__ row_excl,
                                                   int* __restrict__ cursor,
                                                   int* __restrict__ btot) {
    __shared__ int woff[16];
    __shared__ int tot_s;
    const int b = blockIdx.x, t = threadIdx.x;
    const int lane = t & 63, wid = t >> 6;
    const int i = b * 1000 + t;
    int v = (t < 1000) ? count[i] : 0;
    int inc = v;
#pragma unroll
    for (int d = 1; d < 64; d <<= 1) {
        int u = __shfl_up(inc, d, 64);
        if (lane >= d) inc += u;
    }
    if (lane == 63) woff[wid] = inc;
    __syncthreads();
    if (t < 16) {
        int s = woff[t];
        int sc = s;
#pragma unroll
        for (int d = 1; d < 16; d <<= 1) {
            int u = __shfl_up(sc, d, 64);
            if (t >= d) sc += u;
        }
        woff[t] = sc - s;
        if (t == 15) tot_s = sc;
    }
    __syncthreads();
    int excl = woff[wid] + inc - v;
    if (t < 1000) { row_excl[i] = excl; cursor[i] = excl; }
    if (t == 0) btot[b] = tot_s;
}

// K4b: exclusive scan of the 40 block totals -> boff
__global__ __launch_bounds__(64) void scan_tots(const int* __restrict__ btot,
                                                int* __restrict__ boff) {
    const int t = threadIdx.x;
    int v = (t < 40) ? btot[t] : 0;
    int inc = v;
#pragma unroll
    for (int d = 1; d < 64; d <<= 1) {
        int u = __shfl_up(inc, d, 64);
        if (t >= d) inc += u;
    }
    if (t < 40) boff[t] = inc - v;
}

// ---------------------------------------------------------------------------
// K5: slim scatter — only the dst-sorted src ids (4 B/edge).
// ---------------------------------------------------------------------------
__global__ __launch_bounds__(256) void scatter_edges(const int* __restrict__ src,
                                                     const int* __restrict__ dst,
                                                     int* __restrict__ cursor,
                                                     const int* __restrict__ boff,
                                                     int* __restrict__ src_sorted) {
    int e = blockIdx.x * 256 + threadIdx.x;
    int s = src[e], d = dst[e];
    int pos = atomicAdd(&cursor[d], 1) + boff[d / 1000];
    src_sorted[pos] = s;
}

// ---------------------------------------------------------------------------
// K6: aggregation. Persistent waves: exactly resident capacity (2048 blocks
// x 4 waves = 8192 waves at 8 waves/SIMD), each wave strides over ~5 nodes
// (n = wgid + k*8192). Per-SIMD work averages over ~40 nodes -> degree
// imbalance no longer leaks into occupancy (was: block retired on max of 4
// consecutive nodes' degrees).
// Full 8-edge batches take an unguarded fast path (no rem selects); masked
// tail handles cnt%8. h16 gathers issue before the score chain so all 8 are
// in flight under the exp computation.
// ---------------------------------------------------------------------------
__global__ __launch_bounds__(256) void aggregate(const int* __restrict__ src_sorted,
                                                 const unsigned short* __restrict__ h16,
                                                 const float* __restrict__ s_src,
                                                 const float* __restrict__ s_dst,
                                                 const int* __restrict__ row_excl,
                                                 const int* __restrict__ boff,
                                                 const int* __restrict__ count,
                                                 const float* __restrict__ bias,
                                                 float* __restrict__ out) {
    const int t = threadIdx.x;
    const int wave = t >> 6, lane = t & 63;
    const int wgid = blockIdx.x * 4 + wave;   // 0..8191
    const int ch0 = lane * 4;
    const int hh = lane >> 3;

    auto bf2f = [](short v) { return __uint_as_float(((unsigned)(unsigned short)v) << 16); };
    const float4 b4 = *(const float4*)&bias[ch0];

    for (int n = wgid; n < N_NODES; n += 8192) {
        const int start = row_excl[n] + boff[n / 1000];
        const int cnt = count[n];
        const float sd = s_dst[n * 8 + hh];

        float a0 = 0.f, a1 = 0.f, a2 = 0.f, a3 = 0.f, den = 0.f;

        int base = 0;
        // ---- full 8-edge batches: no masking ----
        for (; base + 8 <= cnt; base += 8) {
            int idx = start + base;
            int s[8];
#pragma unroll
            for (int u = 0; u < 8; ++u)
                s[u] = src_sorted[idx + u];

            short4v v[8];
#pragma unroll
            for (int u = 0; u < 8; ++u)
                v[u] = *(const short4v*)&h16[(size_t)s[u] * C_OUT + ch0];

            float w[8];
#pragma unroll
            for (int u = 0; u < 8; ++u) {
                float e = s_src[s[u] * 8 + hh] + sd;
                e = e >= 0.f ? e : NEG_SLOPE * e;
                w[u] = __expf(e);
            }

#pragma unroll
            for (int u = 0; u < 8; ++u) {
                a0 += w[u] * bf2f(v[u][0]);
                a1 += w[u] * bf2f(v[u][1]);
                a2 += w[u] * bf2f(v[u][2]);
                a3 += w[u] * bf2f(v[u][3]);
                den += w[u];
            }
        }

        // ---- masked tail (0..7 edges) ----
        int rem = cnt - base;
        if (rem > 0) {
            int idx = start + base;
            int s[8];
#pragma unroll
            for (int u = 0; u < 8; ++u)
                s[u] = (u < rem) ? src_sorted[idx + u] : 0;

            short4v v[8];
#pragma unroll
            for (int u = 0; u < 8; ++u)
                v[u] = *(const short4v*)&h16[(size_t)s[u] * C_OUT + ch0];

            float w[8];
#pragma unroll
            for (int u = 0; u < 8; ++u) {
                float e = s_src[s[u] * 8 + hh] + sd;
                e = e >= 0.f ? e : NEG_SLOPE * e;
                w[u] = (u < rem) ? __expf(e) : 0.f;
            }

#pragma unroll
            for (int u = 0; u < 8; ++u) {
                a0 += w[u] * bf2f(v[u][0]);
                a1 += w[u] * bf2f(v[u][1]);
                a2 += w[u] * bf2f(v[u][2]);
                a3 += w[u] * bf2f(v[u][3]);
                den += w[u];
            }
        }

        float inv = 1.0f / (den + EPS_F);
        float4 o;
        o.x = a0 * inv + b4.x;
        o.y = a1 * inv + b4.y;
        o.z = a2 * inv + b4.z;
        o.w = a3 * inv + b4.w;
        *(float4*)&out[(size_t)n * C_OUT + ch0] = o;
    }
}

// ---------------------------------------------------------------------------
extern "C" void kernel_launch(void* const* d_in, const int* in_sizes, int n_in,
                              void* d_out, int out_size, void* d_ws, size_t ws_size,
                              hipStream_t stream) {
    const float* x     = (const float*)d_in[0];
    const int*   eidx  = (const int*)d_in[1];
    const float* W     = (const float*)d_in[2];
    const float* a_src = (const float*)d_in[3];
    const float* a_dst = (const float*)d_in[4];
    const float* bias  = (const float*)d_in[5];
    float* out = (float*)d_out;

    const int* src = eidx;
    const int* dst = eidx + N_EDGES;

    char* p = (char*)d_ws;
    auto carve = [&](size_t bytes) {
        char* r = p;
        p += (bytes + 255) & ~(size_t)255;
        return r;
    };
    unsigned short* h16 = (unsigned short*)carve((size_t)N_NODES * C_OUT * 2); // 20.48 MB
    float* s_src      = (float*)carve((size_t)N_NODES * HEADS * 4);
    float* s_dst      = (float*)carve((size_t)N_NODES * HEADS * 4);
    int*   src_sorted = (int*)carve((size_t)N_EDGES * 4);
    int*   count      = (int*)carve((size_t)N_NODES * 4);
    int*   row_excl   = (int*)carve((size_t)N_NODES * 4);
    int*   cursor     = (int*)carve((size_t)N_NODES * 4);
    int*   btot       = (int*)carve(64 * 4);
    int*   boff       = (int*)carve(64 * 4);
    unsigned short* Bp = (unsigned short*)carve((size_t)131072 * 2);           // 256 KB

    hipMemsetAsync(count, 0, (size_t)N_NODES * 4, stream);

    pack_and_count<<<512 + N_EDGES / 256, 256, 0, stream>>>(W, Bp, dst, count);
    gemm_mfma<<<625, 512, 0, stream>>>(x, Bp, a_src, a_dst, h16, s_src, s_dst);
    scan_local<<<40, 1024, 0, stream>>>(count, row_excl, cursor, btot);
    scan_tots<<<1, 64, 0, stream>>>(btot, boff);
    scatter_edges<<<N_EDGES / 256, 256, 0, stream>>>(src, dst, cursor, boff, src_sorted);
    aggregate<<<2048, 256, 0, stream>>>(src_sorted, h16, s_src, s_dst,
                                        row_excl, boff, count, bias, out);
}

// Round 4
// 297.996 us; speedup vs baseline: 1.0552x; 1.0077x over previous
//
#include <hip/hip_runtime.h>
#include <hip/hip_bf16.h>
#include <math.h>
#include <stdint.h>

#define N_NODES 40000
#define N_EDGES 640000
#define F_IN    512
#define F_OUT   32
#define HEADS   8
#define C_OUT   (HEADS * F_OUT)   // 256
#define NEG_SLOPE 0.2f
#define EPS_F   1e-16f

typedef __attribute__((ext_vector_type(8)))  short  short8;
typedef __attribute__((ext_vector_type(4)))  short  short4v;
typedef __attribute__((ext_vector_type(16))) float  float16v;

// truncating fp32 -> (hi,lo) bf16 split: hi+lo represents f to ~2^-17 rel
__device__ __forceinline__ void splitT(float f, unsigned short& hi, unsigned short& lo) {
    unsigned u = __float_as_uint(f);
    hi = (unsigned short)(u >> 16);
    float r = f - __uint_as_float(u & 0xFFFF0000u);
    lo = (unsigned short)(__float_as_uint(r) >> 16);
}

__device__ __forceinline__ unsigned short f2bf(float f) {
    unsigned u = __float_as_uint(f);
    return (unsigned short)((u + 0x7FFF + ((u >> 16) & 1)) >> 16);
}

// ---------------------------------------------------------------------------
// K0: fused pack_W + count_edges (independent work, one launch).
// Blocks [0,512): pack W into per-lane B-fragment layout for
// mfma_f32_32x32x16_bf16.
// Bp[wc(4)][ktg(32)][ni(2)][lane(64)][j(8)], value =
//   B[k = ktg*16 + (lane>>5)*8 + j][col = wc*64 + ni*32 + (lane&31)]
// where B[k][col] = W[col>>5][k][col&31].
// Blocks [512, 512+2500): per-dst in-degree counts.
// ---------------------------------------------------------------------------
__global__ __launch_bounds__(256) void pack_and_count(const float* __restrict__ W,
                                                      unsigned short* __restrict__ Bp,
                                                      const int* __restrict__ dst,
                                                      int* __restrict__ count) {
    if (blockIdx.x < 512) {
        int tid = blockIdx.x * 256 + threadIdx.x;   // 131072 total
        int j    = tid & 7;
        int L    = (tid >> 3) & 63;
        int ni   = (tid >> 9) & 1;
        int ktg  = (tid >> 10) & 31;
        int wc   = tid >> 15;                        // 0..3
        int k    = ktg * 16 + (L >> 5) * 8 + j;
        int col  = wc * 64 + ni * 32 + (L & 31);
        int hh = col >> 5, f = col & 31;
        Bp[tid] = f2bf(W[hh * (F_IN * F_OUT) + k * F_OUT + f]);
    } else {
        int e = (blockIdx.x - 512) * 256 + threadIdx.x;
        atomicAdd(&count[dst[e]], 1);
    }
}

// ---------------------------------------------------------------------------
// K1: MFMA projection GEMM, 32x32x16 bf16, 2-term split ((x_hi+x_lo)*B_hi).
// Block: 256 threads = 4 waves, one wave per 64-col group; tile 32 rows x
// 256 cols; grid 1250 (exact: 1250*32 = 40000). BK=64.
// DOUBLE-BUFFERED LDS -> one barrier per K-step: LDS writes for tile st+1
// overlap MFMA of tile st. Register prefetch runs 2 tiles ahead.
// Load order matters (in-order vmcnt): breg L2 loads issue BEFORE the HBM
// prefetch so the MFMA's vmcnt wait on breg does not drain the prefetch.
// A staged in LDS (stride 66 shorts = 33 banks -> conflict-free frag reads);
// B fragments register-direct from the L2-resident packed buffer.
// Epilogue: h16 stores + fused fp32-exact attention scores.
// ---------------------------------------------------------------------------
#define AS 66   // k-stride in shorts: 64 + 2 pad (33 banks, odd -> bijection)

__global__ __launch_bounds__(256, 4) void gemm_mfma(const float* __restrict__ x,
                                                    const unsigned short* __restrict__ Bp,
                                                    const float* __restrict__ a_src,
                                                    const float* __restrict__ a_dst,
                                                    unsigned short* __restrict__ h16,
                                                    float* __restrict__ s_src,
                                                    float* __restrict__ s_dst) {
    __shared__ unsigned short As_hi[2][32 * AS];
    __shared__ unsigned short As_lo[2][32 * AS];

    const int t = threadIdx.x;
    const int wc = t >> 6, L = t & 63;             // wave = col group 0..3
    const int r31 = L & 31, half = L >> 5;
    const int n0 = blockIdx.x * 32;

    float16v acc[2];
#pragma unroll
    for (int ni = 0; ni < 2; ++ni)
#pragma unroll
        for (int r = 0; r < 16; ++r) acc[ni][r] = 0.f;

    const int kcol = (t & 15) * 4;   // k offset within 64-wide K-tile
    const int rbase = t >> 4;        // 0..15 -> rows rbase, rbase+16
    const float* xr0 = &x[(size_t)(n0 + rbase) * F_IN + kcol];
    const float* xr1 = &x[(size_t)(n0 + rbase + 16) * F_IN + kcol];

    // convert a staged float4 pair -> LDS buffer b (rows rbase, rbase+16)
#define CONVW(b, s0, s1) do {                                                  \
        unsigned short h0,h1,h2,h3,l0,l1,l2,l3;                                \
        splitT((s0).x,h0,l0); splitT((s0).y,h1,l1);                            \
        splitT((s0).z,h2,l2); splitT((s0).w,h3,l3);                            \
        *(short4v*)&As_hi[b][rbase*AS + kcol] =                                \
            (short4v){(short)h0,(short)h1,(short)h2,(short)h3};                \
        *(short4v*)&As_lo[b][rbase*AS + kcol] =                                \
            (short4v){(short)l0,(short)l1,(short)l2,(short)l3};                \
        splitT((s1).x,h0,l0); splitT((s1).y,h1,l1);                            \
        splitT((s1).z,h2,l2); splitT((s1).w,h3,l3);                            \
        *(short4v*)&As_hi[b][(rbase+16)*AS + kcol] =                           \
            (short4v){(short)h0,(short)h1,(short)h2,(short)h3};                \
        *(short4v*)&As_lo[b][(rbase+16)*AS + kcol] =                           \
            (short4v){(short)l0,(short)l1,(short)l2,(short)l3};                \
    } while (0)

    // prologue: tile0 -> LDS[0]; tile1 in flight in stg[1]
    float4 stg[2][2];
    stg[0][0] = *(const float4*)(xr0);
    stg[0][1] = *(const float4*)(xr1);
    CONVW(0, stg[0][0], stg[0][1]);
    stg[1][0] = *(const float4*)(xr0 + 64);
    stg[1][1] = *(const float4*)(xr1 + 64);

#pragma unroll
    for (int st = 0; st < 8; ++st) {
        const int cur = st & 1, nxt = cur ^ 1;
        __syncthreads();   // LDS[cur] (tile st) visible; prev reads of LDS[nxt] done

        // ---- B fragments FIRST (L2): their vmcnt wait must not drain HBM prefetch
        short8 breg[4][2];
#pragma unroll
        for (int kt = 0; kt < 4; ++kt)
#pragma unroll
            for (int ni = 0; ni < 2; ++ni) {
                size_t idx = ((((size_t)wc * 32 + (st * 4 + kt)) * 2 + ni) * 64 + L) * 8;
                breg[kt][ni] = *(const short8*)&Bp[idx];
            }

        // ---- HBM prefetch tile st+2 into the stg slot freed last iteration
        if (st < 6) {
            stg[cur][0] = *(const float4*)(xr0 + (st + 2) * 64);
            stg[cur][1] = *(const float4*)(xr1 + (st + 2) * 64);
        }

        // ---- MFMA: 4 k-steps of 16, 2 ni x 2 terms, A frags from LDS[cur]
#pragma unroll
        for (int kt = 0; kt < 4; ++kt) {
            int off = r31 * AS + kt * 16 + half * 8;
            short8 ah = *(const short8*)&As_hi[cur][off];
            short8 al = *(const short8*)&As_lo[cur][off];
#pragma unroll
            for (int ni = 0; ni < 2; ++ni) {
                acc[ni] = __builtin_amdgcn_mfma_f32_32x32x16_bf16(ah, breg[kt][ni], acc[ni], 0, 0, 0);
                acc[ni] = __builtin_amdgcn_mfma_f32_32x32x16_bf16(al, breg[kt][ni], acc[ni], 0, 0, 0);
            }
        }

        // ---- convert + LDS-write tile st+1 (overlaps MFMA issue; done pre-barrier)
        if (st < 7) CONVW(nxt, stg[nxt][0], stg[nxt][1]);
    }
#undef CONVW

    // ---- epilogue 1: h16 stores ----
    // C/D layout (32x32): col = lane&31, row = (reg&3) + 8*(reg>>2) + 4*half
#pragma unroll
    for (int ni = 0; ni < 2; ++ni) {
        int colb = wc * 64 + ni * 32 + r31;
#pragma unroll
        for (int r = 0; r < 16; ++r) {
            int row = n0 + (r & 3) + 8 * (r >> 2) + 4 * half;
            h16[(size_t)row * C_OUT + colb] = f2bf(acc[ni][r]);
        }
    }

    // ---- epilogue 2: fused attention scores (fp32-exact) ----
    // ni-frag covers exactly one head: hh = wc*2 + ni
#pragma unroll
    for (int ni = 0; ni < 2; ++ni) {
        int hh = wc * 2 + ni;
        float af = a_src[hh * 32 + r31];
        float df = a_dst[hh * 32 + r31];
#pragma unroll
        for (int r = 0; r < 16; ++r) {
            float v = acc[ni][r];
            float vs = v * af;
            float vd = v * df;
#pragma unroll
            for (int m = 1; m < 32; m <<= 1) {
                vs += __shfl_xor(vs, m, 64);
                vd += __shfl_xor(vd, m, 64);
            }
            if (r31 == 0) {
                int row = n0 + (r & 3) + 8 * (r >> 2) + 4 * half;
                s_src[row * 8 + hh] = vs;
                s_dst[row * 8 + hh] = vd;
            }
        }
    }
}

// ---------------------------------------------------------------------------
// K4a: 40-block local exclusive scan (1000/block) + per-block totals
// ---------------------------------------------------------------------------
__global__ __launch_bounds__(1024) void scan_local(const int* __restrict__ count,
                                                   int* __restrict__ row_excl,
                                                   int* __restrict__ cursor,
                                                   int* __restrict__ btot) {
    __shared__ int woff[16];
    __shared__ int tot_s;
    const int b = blockIdx.x, t = threadIdx.x;
    const int lane = t & 63, wid = t >> 6;
    const int i = b * 1000 + t;
    int v = (t < 1000) ? count[i] : 0;
    int inc = v;
#pragma unroll
    for (int d = 1; d < 64; d <<= 1) {
        int u = __shfl_up(inc, d, 64);
        if (lane >= d) inc += u;
    }
    if (lane == 63) woff[wid] = inc;
    __syncthreads();
    if (t < 16) {
        int s = woff[t];
        int sc = s;
#pragma unroll
        for (int d = 1; d < 16; d <<= 1) {
            int u = __shfl_up(sc, d, 64);
            if (t >= d) sc += u;
        }
        woff[t] = sc - s;
        if (t == 15) tot_s = sc;
    }
    __syncthreads();
    int excl = woff[wid] + inc - v;
    if (t < 1000) { row_excl[i] = excl; cursor[i] = excl; }
    if (t == 0) btot[b] = tot_s;
}

// K4b: exclusive scan of the 40 block totals -> boff
__global__ __launch_bounds__(64) void scan_tots(const int* __restrict__ btot,
                                                int* __restrict__ boff) {
    const int t = threadIdx.x;
    int v = (t < 40) ? btot[t] : 0;
    int inc = v;
#pragma unroll
    for (int d = 1; d < 64; d <<= 1) {
        int u = __shfl_up(inc, d, 64);
        if (t >= d) inc += u;
    }
    if (t < 40) boff[t] = inc - v;
}

// ---------------------------------------------------------------------------
// K5: slim scatter — only the dst-sorted src ids (4 B/edge).
// ---------------------------------------------------------------------------
__global__ __launch_bounds__(256) void scatter_edges(const int* __restrict__ src,
                                                     const int* __restrict__ dst,
                                                     int* __restrict__ cursor,
                                                     const int* __restrict__ boff,
                                                     int* __restrict__ src_sorted) {
    int e = blockIdx.x * 256 + threadIdx.x;
    int s = src[e], d = dst[e];
    int pos = atomicAdd(&cursor[d], 1) + boff[d / 1000];
    src_sorted[pos] = s;
}

// ---------------------------------------------------------------------------
// K6: aggregation. Persistent waves: exactly resident capacity (2048 blocks
// x 4 waves = 8192 waves at 8 waves/SIMD), each wave strides over ~5 nodes
// (n = wgid + k*8192). Per-SIMD work averages over ~40 nodes -> degree
// imbalance no longer leaks into occupancy.
// Full 8-edge batches take an unguarded fast path (no rem selects); masked
// tail handles cnt%8. h16 gathers issue before the score chain so all 8 are
// in flight under the exp computation.
// ---------------------------------------------------------------------------
__global__ __launch_bounds__(256) void aggregate(const int* __restrict__ src_sorted,
                                                 const unsigned short* __restrict__ h16,
                                                 const float* __restrict__ s_src,
                                                 const float* __restrict__ s_dst,
                                                 const int* __restrict__ row_excl,
                                                 const int* __restrict__ boff,
                                                 const int* __restrict__ count,
                                                 const float* __restrict__ bias,
                                                 float* __restrict__ out) {
    const int t = threadIdx.x;
    const int wave = t >> 6, lane = t & 63;
    const int wgid = blockIdx.x * 4 + wave;   // 0..8191
    const int ch0 = lane * 4;
    const int hh = lane >> 3;

    auto bf2f = [](short v) { return __uint_as_float(((unsigned)(unsigned short)v) << 16); };
    const float4 b4 = *(const float4*)&bias[ch0];

    for (int n = wgid; n < N_NODES; n += 8192) {
        const int start = row_excl[n] + boff[n / 1000];
        const int cnt = count[n];
        const float sd = s_dst[n * 8 + hh];

        float a0 = 0.f, a1 = 0.f, a2 = 0.f, a3 = 0.f, den = 0.f;

        int base = 0;
        // ---- full 8-edge batches: no masking ----
        for (; base + 8 <= cnt; base += 8) {
            int idx = start + base;
            int s[8];
#pragma unroll
            for (int u = 0; u < 8; ++u)
                s[u] = src_sorted[idx + u];

            short4v v[8];
#pragma unroll
            for (int u = 0; u < 8; ++u)
                v[u] = *(const short4v*)&h16[(size_t)s[u] * C_OUT + ch0];

            float w[8];
#pragma unroll
            for (int u = 0; u < 8; ++u) {
                float e = s_src[s[u] * 8 + hh] + sd;
                e = e >= 0.f ? e : NEG_SLOPE * e;
                w[u] = __expf(e);
            }

#pragma unroll
            for (int u = 0; u < 8; ++u) {
                a0 += w[u] * bf2f(v[u][0]);
                a1 += w[u] * bf2f(v[u][1]);
                a2 += w[u] * bf2f(v[u][2]);
                a3 += w[u] * bf2f(v[u][3]);
                den += w[u];
            }
        }

        // ---- masked tail (0..7 edges) ----
        int rem = cnt - base;
        if (rem > 0) {
            int idx = start + base;
            int s[8];
#pragma unroll
            for (int u = 0; u < 8; ++u)
                s[u] = (u < rem) ? src_sorted[idx + u] : 0;

            short4v v[8];
#pragma unroll
            for (int u = 0; u < 8; ++u)
                v[u] = *(const short4v*)&h16[(size_t)s[u] * C_OUT + ch0];

            float w[8];
#pragma unroll
            for (int u = 0; u < 8; ++u) {
                float e = s_src[s[u] * 8 + hh] + sd;
                e = e >= 0.f ? e : NEG_SLOPE * e;
                w[u] = (u < rem) ? __expf(e) : 0.f;
            }

#pragma unroll
            for (int u = 0; u < 8; ++u) {
                a0 += w[u] * bf2f(v[u][0]);
                a1 += w[u] * bf2f(v[u][1]);
                a2 += w[u] * bf2f(v[u][2]);
                a3 += w[u] * bf2f(v[u][3]);
                den += w[u];
            }
        }

        float inv = 1.0f / (den + EPS_F);
        float4 o;
        o.x = a0 * inv + b4.x;
        o.y = a1 * inv + b4.y;
        o.z = a2 * inv + b4.z;
        o.w = a3 * inv + b4.w;
        *(float4*)&out[(size_t)n * C_OUT + ch0] = o;
    }
}

// ---------------------------------------------------------------------------
extern "C" void kernel_launch(void* const* d_in, const int* in_sizes, int n_in,
                              void* d_out, int out_size, void* d_ws, size_t ws_size,
                              hipStream_t stream) {
    const float* x     = (const float*)d_in[0];
    const int*   eidx  = (const int*)d_in[1];
    const float* W     = (const float*)d_in[2];
    const float* a_src = (const float*)d_in[3];
    const float* a_dst = (const float*)d_in[4];
    const float* bias  = (const float*)d_in[5];
    float* out = (float*)d_out;

    const int* src = eidx;
    const int* dst = eidx + N_EDGES;

    char* p = (char*)d_ws;
    auto carve = [&](size_t bytes) {
        char* r = p;
        p += (bytes + 255) & ~(size_t)255;
        return r;
    };
    unsigned short* h16 = (unsigned short*)carve((size_t)N_NODES * C_OUT * 2); // 20.48 MB
    float* s_src      = (float*)carve((size_t)N_NODES * HEADS * 4);
    float* s_dst      = (float*)carve((size_t)N_NODES * HEADS * 4);
    int*   src_sorted = (int*)carve((size_t)N_EDGES * 4);
    int*   count      = (int*)carve((size_t)N_NODES * 4);
    int*   row_excl   = (int*)carve((size_t)N_NODES * 4);
    int*   cursor     = (int*)carve((size_t)N_NODES * 4);
    int*   btot       = (int*)carve(64 * 4);
    int*   boff       = (int*)carve(64 * 4);
    unsigned short* Bp = (unsigned short*)carve((size_t)131072 * 2);           // 256 KB

    hipMemsetAsync(count, 0, (size_t)N_NODES * 4, stream);

    pack_and_count<<<512 + N_EDGES / 256, 256, 0, stream>>>(W, Bp, dst, count);
    gemm_mfma<<<1250, 256, 0, stream>>>(x, Bp, a_src, a_dst, h16, s_src, s_dst);
    scan_local<<<40, 1024, 0, stream>>>(count, row_excl, cursor, btot);
    scan_tots<<<1, 64, 0, stream>>>(btot, boff);
    scatter_edges<<<N_EDGES / 256, 256, 0, stream>>>(src, dst, cursor, boff, src_sorted);
    aggregate<<<2048, 256, 0, stream>>>(src_sorted, h16, s_src, s_dst,
                                        row_excl, boff, count, bias, out);
}